// Round 1
// baseline (1196.992 us; speedup 1.0000x reference)
//
#include <hip/hip_runtime.h>

// Problem constants
#define BB 8
#define NN 1024
#define CC 768
#define HH 12
#define HD 64
#define RR 16
#define MM (BB * NN)  // 8192 rows

// softmax scale folded with log2(e) for exp2f: SCALE * 1.4426950408889634
#define KSC 0.1803368801111244f

// ---------------------------------------------------------------------------
// Kernel 1: LoRA down-projection  xa[z][m][r] = bw[z] * sum_k x[m,k] * la_z[k,r]
// One block per row m; 192 threads = 48 cols x 4 K-chunks.
// ---------------------------------------------------------------------------
__global__ __launch_bounds__(192) void lora_down(const float* __restrict__ x,
                                                 const float* __restrict__ la_q,
                                                 const float* __restrict__ la_k,
                                                 const float* __restrict__ la_v,
                                                 const float* __restrict__ bw,
                                                 float* __restrict__ xa) {
    __shared__ float xs[CC];
    __shared__ float part[4][48];
    const int m = blockIdx.x;
    for (int i = threadIdx.x; i < CC; i += 192) xs[i] = x[(size_t)m * CC + i];
    __syncthreads();

    const int c = threadIdx.x % 48;   // adapter*16 + r
    const int chunk = threadIdx.x / 48;  // 0..3
    const int a = c / 16, r = c % 16;
    const float* la = (a == 0) ? la_q : (a == 1) ? la_k : la_v;
    float s = 0.f;
    const int k0 = chunk * 192;
    #pragma unroll 4
    for (int k = k0; k < k0 + 192; ++k) s += xs[k] * la[k * RR + r];
    part[chunk][c] = s;
    __syncthreads();

    if (threadIdx.x < 48) {
        const int a2 = threadIdx.x / 16, r2 = threadIdx.x % 16;
        float v = part[0][threadIdx.x] + part[1][threadIdx.x] +
                  part[2][threadIdx.x] + part[3][threadIdx.x];
        xa[(size_t)a2 * MM * RR + (size_t)m * RR + r2] = v * bw[a2];
    }
}

// ---------------------------------------------------------------------------
// Kernel 2: fused QKV GEMM + LoRA up-projection, head-split store.
// out_z[m,c] = sum_k x[m,k] W_z[k,c] + sum_r xa_z[m,r] lb_z[r,c]   (bw folded in xa)
// Tile 128x128, BK=16, 256 threads, 8x8 per thread. z = blockIdx.z picks q/k/v.
// Store layout: [B, H, N, HD] for the attention kernel.
// ---------------------------------------------------------------------------
__global__ __launch_bounds__(256) void qkv_gemm(const float* __restrict__ x,
                                                const float* __restrict__ Wq,
                                                const float* __restrict__ Wk,
                                                const float* __restrict__ Wv,
                                                const float* __restrict__ xa,
                                                const float* __restrict__ lbq,
                                                const float* __restrict__ lbk,
                                                const float* __restrict__ lbv,
                                                float* __restrict__ qd,
                                                float* __restrict__ kd,
                                                float* __restrict__ vd) {
    __shared__ __align__(16) float As[16][132];  // A transposed: As[k][row], pad->2-way max
    __shared__ __align__(16) float Bs[16][128];  // B natural:    Bs[k][col]

    const int z = blockIdx.z;
    const float* W   = (z == 0) ? Wq  : (z == 1) ? Wk  : Wv;
    const float* lbp = (z == 0) ? lbq : (z == 1) ? lbk : lbv;
    const float* xz  = xa + (size_t)z * MM * RR;
    float* dst       = (z == 0) ? qd  : (z == 1) ? kd  : vd;

    const int m0 = blockIdx.y * 128;
    const int c0 = blockIdx.x * 128;
    const int tid = threadIdx.x;
    const int tx = tid & 15, ty = tid >> 4;
    const int alr = tid >> 2;            // A-load row (0..63), +64 second pass
    const int alc = (tid & 3) * 4;       // A-load col (k within tile)
    const int blk = tid >> 5;            // B-load row (0..7), +8 second pass
    const int blc = (tid & 31) * 4;      // B-load col

    float acc[8][8] = {};

    for (int kt = 0; kt < CC; kt += 16) {
        #pragma unroll
        for (int p = 0; p < 2; ++p) {
            float4 a = *(const float4*)&x[(size_t)(m0 + alr + 64 * p) * CC + kt + alc];
            As[alc + 0][alr + 64 * p] = a.x;
            As[alc + 1][alr + 64 * p] = a.y;
            As[alc + 2][alr + 64 * p] = a.z;
            As[alc + 3][alr + 64 * p] = a.w;
            *(float4*)&Bs[blk + 8 * p][blc] =
                *(const float4*)&W[(size_t)(kt + blk + 8 * p) * CC + c0 + blc];
        }
        __syncthreads();
        #pragma unroll
        for (int kk = 0; kk < 16; ++kk) {
            float4 a0 = *(const float4*)&As[kk][ty * 8];
            float4 a1 = *(const float4*)&As[kk][ty * 8 + 4];
            float4 b0 = *(const float4*)&Bs[kk][tx * 4];
            float4 b1 = *(const float4*)&Bs[kk][tx * 4 + 64];
            float av[8] = {a0.x, a0.y, a0.z, a0.w, a1.x, a1.y, a1.z, a1.w};
            float bv[8] = {b0.x, b0.y, b0.z, b0.w, b1.x, b1.y, b1.z, b1.w};
            #pragma unroll
            for (int i = 0; i < 8; ++i)
                #pragma unroll
                for (int j = 0; j < 8; ++j) acc[i][j] += av[i] * bv[j];
        }
        __syncthreads();
    }

    // LoRA rank-16 epilogue: acc += xa_z[rows,16] @ lb_z[16,cols]
    {
        #pragma unroll
        for (int p = 0; p < 2; ++p)
            *(float4*)&Bs[blk + 8 * p][blc] =
                *(const float4*)&lbp[(size_t)(blk + 8 * p) * CC + c0 + blc];
        #pragma unroll
        for (int p = 0; p < 2; ++p) {
            int idx = tid + 256 * p;          // float4 index over 128x16 tile
            int row = idx >> 2, r4 = (idx & 3) * 4;
            float4 a = *(const float4*)&xz[(size_t)(m0 + row) * RR + r4];
            As[r4 + 0][row] = a.x;
            As[r4 + 1][row] = a.y;
            As[r4 + 2][row] = a.z;
            As[r4 + 3][row] = a.w;
        }
        __syncthreads();
        #pragma unroll
        for (int r = 0; r < 16; ++r) {
            float4 a0 = *(const float4*)&As[r][ty * 8];
            float4 a1 = *(const float4*)&As[r][ty * 8 + 4];
            float4 b0 = *(const float4*)&Bs[r][tx * 4];
            float4 b1 = *(const float4*)&Bs[r][tx * 4 + 64];
            float av[8] = {a0.x, a0.y, a0.z, a0.w, a1.x, a1.y, a1.z, a1.w};
            float bv[8] = {b0.x, b0.y, b0.z, b0.w, b1.x, b1.y, b1.z, b1.w};
            #pragma unroll
            for (int i = 0; i < 8; ++i)
                #pragma unroll
                for (int j = 0; j < 8; ++j) acc[i][j] += av[i] * bv[j];
        }
    }

    // head-split store to [B, H, N, HD]
    #pragma unroll
    for (int i = 0; i < 8; ++i) {
        const int m = m0 + ty * 8 + i;
        const int b = m >> 10, n = m & 1023;
        #pragma unroll
        for (int g = 0; g < 2; ++g) {
            const int c = c0 + g * 64 + tx * 4;
            const int h = c >> 6, d = c & 63;
            float4 v = make_float4(acc[i][4 * g + 0], acc[i][4 * g + 1],
                                   acc[i][4 * g + 2], acc[i][4 * g + 3]);
            *(float4*)&dst[(((size_t)(b * HH + h)) * NN + n) * HD + d] = v;
        }
    }
}

// ---------------------------------------------------------------------------
// Kernel 3: flash attention (fp32). One block = one (b,h) x 64 q-rows.
// 256 threads: qg = tid>>3 owns q-rows {2qg, 2qg+1}; kg = tid&7 owns
// k-columns 8kg..8kg+7 in QK^T and output dims 8kg..8kg+7 in PV.
// Online softmax; P broadcast via width-8 shuffles (no LDS P tile).
// K-row reads XOR-rotated by kg to avoid stride-8-row bank conflicts.
// ---------------------------------------------------------------------------
__global__ __launch_bounds__(256) void attn_kernel(const float* __restrict__ qh,
                                                   const float* __restrict__ kh,
                                                   const float* __restrict__ vh,
                                                   float* __restrict__ o) {
    __shared__ __align__(16) float Qs[64][68];
    __shared__ __align__(16) float Ks[64][68];
    __shared__ __align__(16) float Vs[64][68];

    const int bh = blockIdx.y;            // 0..95
    const int q0 = blockIdx.x * 64;
    const float* qp = qh + (size_t)bh * NN * HD;
    const float* kp = kh + (size_t)bh * NN * HD;
    const float* vp = vh + (size_t)bh * NN * HD;

    const int tid = threadIdx.x;
    const int qg = tid >> 3;  // 0..31
    const int kg = tid & 7;   // 0..7
    const int lr = tid >> 4, lc4 = (tid & 15) * 4;  // staging map

    // stage Q tile once
    #pragma unroll
    for (int p = 0; p < 4; ++p)
        *(float4*)&Qs[lr + 16 * p][lc4] =
            *(const float4*)&qp[(size_t)(q0 + lr + 16 * p) * HD + lc4];

    float m_run[2] = {-1e30f, -1e30f};
    float l_run[2] = {0.f, 0.f};
    float oacc[2][8];
    #pragma unroll
    for (int i = 0; i < 2; ++i)
        #pragma unroll
        for (int j = 0; j < 8; ++j) oacc[i][j] = 0.f;

    for (int t = 0; t < NN / 64; ++t) {
        __syncthreads();  // protect Ks/Vs (prev iter) and Qs (first iter)
        #pragma unroll
        for (int p = 0; p < 4; ++p) {
            *(float4*)&Ks[lr + 16 * p][lc4] =
                *(const float4*)&kp[(size_t)(t * 64 + lr + 16 * p) * HD + lc4];
            *(float4*)&Vs[lr + 16 * p][lc4] =
                *(const float4*)&vp[(size_t)(t * 64 + lr + 16 * p) * HD + lc4];
        }
        __syncthreads();

        // S = Q K^T : p2[i][jj] is score for column (8*kg + (jj^kg))
        float p2[2][8];
        #pragma unroll
        for (int i = 0; i < 2; ++i)
            #pragma unroll
            for (int j = 0; j < 8; ++j) p2[i][j] = 0.f;
        for (int d4 = 0; d4 < 16; ++d4) {
            float4 qv0 = *(const float4*)&Qs[2 * qg + 0][d4 * 4];
            float4 qv1 = *(const float4*)&Qs[2 * qg + 1][d4 * 4];
            #pragma unroll
            for (int jj = 0; jj < 8; ++jj) {
                float4 kv = *(const float4*)&Ks[8 * kg + (jj ^ kg)][d4 * 4];
                p2[0][jj] += qv0.x * kv.x + qv0.y * kv.y + qv0.z * kv.z + qv0.w * kv.w;
                p2[1][jj] += qv1.x * kv.x + qv1.y * kv.y + qv1.z * kv.z + qv1.w * kv.w;
            }
        }

        // online softmax (raw-score max tracking; SCALE folded into exp2)
        float tm[2];
        #pragma unroll
        for (int i = 0; i < 2; ++i) {
            tm[i] = p2[i][0];
            #pragma unroll
            for (int j = 1; j < 8; ++j) tm[i] = fmaxf(tm[i], p2[i][j]);
        }
        #pragma unroll
        for (int w = 1; w < 8; w <<= 1) {
            tm[0] = fmaxf(tm[0], __shfl_xor(tm[0], w, 8));
            tm[1] = fmaxf(tm[1], __shfl_xor(tm[1], w, 8));
        }
        float ls[2];
        #pragma unroll
        for (int i = 0; i < 2; ++i) {
            const float nm = fmaxf(m_run[i], tm[i]);
            const float sc = exp2f((m_run[i] - nm) * KSC);
            m_run[i] = nm;
            ls[i] = 0.f;
            #pragma unroll
            for (int j = 0; j < 8; ++j) {
                const float e = exp2f((p2[i][j] - nm) * KSC);
                p2[i][j] = e;
                ls[i] += e;
            }
            l_run[i] = l_run[i] * sc;
            #pragma unroll
            for (int j = 0; j < 8; ++j) oacc[i][j] *= sc;
        }
        #pragma unroll
        for (int w = 1; w < 8; w <<= 1) {
            ls[0] += __shfl_xor(ls[0], w, 8);
            ls[1] += __shfl_xor(ls[1], w, 8);
        }
        l_run[0] += ls[0];
        l_run[1] += ls[1];

        // PV: oacc[i][d'] += sum_kj P[i][kj] * V[kj][8kg+d']
        #pragma unroll
        for (int kj = 0; kj < 64; ++kj) {
            const int src = kj >> 3;
            const int reg = (kj & 7) ^ src;
            const float pb0 = __shfl(p2[0][reg], src, 8);
            const float pb1 = __shfl(p2[1][reg], src, 8);
            const float4 v0 = *(const float4*)&Vs[kj][8 * kg];
            const float4 v1 = *(const float4*)&Vs[kj][8 * kg + 4];
            oacc[0][0] += pb0 * v0.x; oacc[0][1] += pb0 * v0.y;
            oacc[0][2] += pb0 * v0.z; oacc[0][3] += pb0 * v0.w;
            oacc[0][4] += pb0 * v1.x; oacc[0][5] += pb0 * v1.y;
            oacc[0][6] += pb0 * v1.z; oacc[0][7] += pb0 * v1.w;
            oacc[1][0] += pb1 * v0.x; oacc[1][1] += pb1 * v0.y;
            oacc[1][2] += pb1 * v0.z; oacc[1][3] += pb1 * v0.w;
            oacc[1][4] += pb1 * v1.x; oacc[1][5] += pb1 * v1.y;
            oacc[1][6] += pb1 * v1.z; oacc[1][7] += pb1 * v1.w;
        }
    }

    // finalize + store merged [B, N, C]
    const int b = bh / HH, h = bh % HH;
    #pragma unroll
    for (int i = 0; i < 2; ++i) {
        const int n = q0 + 2 * qg + i;
        const float inv = 1.f / l_run[i];
        float4 w0 = make_float4(oacc[i][0] * inv, oacc[i][1] * inv,
                                oacc[i][2] * inv, oacc[i][3] * inv);
        float4 w1 = make_float4(oacc[i][4] * inv, oacc[i][5] * inv,
                                oacc[i][6] * inv, oacc[i][7] * inv);
        float* op = &o[((size_t)b * NN + n) * CC + h * HD + 8 * kg];
        *(float4*)&op[0] = w0;
        *(float4*)&op[4] = w1;
    }
}

// ---------------------------------------------------------------------------
// Kernel 4: output projection  out[m,c] = sum_k o[m,k] Wp[k,c] + bp[c]
// Same 128x128x16 SGEMM structure.
// ---------------------------------------------------------------------------
__global__ __launch_bounds__(256) void proj_gemm(const float* __restrict__ A,
                                                 const float* __restrict__ Wp,
                                                 const float* __restrict__ bp,
                                                 float* __restrict__ out) {
    __shared__ __align__(16) float As[16][132];
    __shared__ __align__(16) float Bs[16][128];

    const int m0 = blockIdx.y * 128;
    const int c0 = blockIdx.x * 128;
    const int tid = threadIdx.x;
    const int tx = tid & 15, ty = tid >> 4;
    const int alr = tid >> 2;
    const int alc = (tid & 3) * 4;
    const int blk = tid >> 5;
    const int blc = (tid & 31) * 4;

    float acc[8][8] = {};

    for (int kt = 0; kt < CC; kt += 16) {
        #pragma unroll
        for (int p = 0; p < 2; ++p) {
            float4 a = *(const float4*)&A[(size_t)(m0 + alr + 64 * p) * CC + kt + alc];
            As[alc + 0][alr + 64 * p] = a.x;
            As[alc + 1][alr + 64 * p] = a.y;
            As[alc + 2][alr + 64 * p] = a.z;
            As[alc + 3][alr + 64 * p] = a.w;
            *(float4*)&Bs[blk + 8 * p][blc] =
                *(const float4*)&Wp[(size_t)(kt + blk + 8 * p) * CC + c0 + blc];
        }
        __syncthreads();
        #pragma unroll
        for (int kk = 0; kk < 16; ++kk) {
            float4 a0 = *(const float4*)&As[kk][ty * 8];
            float4 a1 = *(const float4*)&As[kk][ty * 8 + 4];
            float4 b0 = *(const float4*)&Bs[kk][tx * 4];
            float4 b1 = *(const float4*)&Bs[kk][tx * 4 + 64];
            float av[8] = {a0.x, a0.y, a0.z, a0.w, a1.x, a1.y, a1.z, a1.w};
            float bv[8] = {b0.x, b0.y, b0.z, b0.w, b1.x, b1.y, b1.z, b1.w};
            #pragma unroll
            for (int i = 0; i < 8; ++i)
                #pragma unroll
                for (int j = 0; j < 8; ++j) acc[i][j] += av[i] * bv[j];
        }
        __syncthreads();
    }

    const float4 bb0 = *(const float4*)&bp[c0 + tx * 4];
    const float4 bb1 = *(const float4*)&bp[c0 + tx * 4 + 64];
    #pragma unroll
    for (int i = 0; i < 8; ++i) {
        const int m = m0 + ty * 8 + i;
        float4 v0 = make_float4(acc[i][0] + bb0.x, acc[i][1] + bb0.y,
                                acc[i][2] + bb0.z, acc[i][3] + bb0.w);
        float4 v1 = make_float4(acc[i][4] + bb1.x, acc[i][5] + bb1.y,
                                acc[i][6] + bb1.z, acc[i][7] + bb1.w);
        *(float4*)&out[(size_t)m * CC + c0 + tx * 4] = v0;
        *(float4*)&out[(size_t)m * CC + c0 + tx * 4 + 64] = v1;
    }
}

// ---------------------------------------------------------------------------
extern "C" void kernel_launch(void* const* d_in, const int* in_sizes, int n_in,
                              void* d_out, int out_size, void* d_ws, size_t ws_size,
                              hipStream_t stream) {
    const float* x    = (const float*)d_in[0];
    const float* Wq   = (const float*)d_in[1];
    const float* Wk   = (const float*)d_in[2];
    const float* Wv   = (const float*)d_in[3];
    const float* Wp   = (const float*)d_in[4];
    const float* bp   = (const float*)d_in[5];
    const float* la_q = (const float*)d_in[6];
    const float* lb_q = (const float*)d_in[7];
    const float* la_k = (const float*)d_in[8];
    const float* lb_k = (const float*)d_in[9];
    const float* la_v = (const float*)d_in[10];
    const float* lb_v = (const float*)d_in[11];
    const float* bw   = (const float*)d_in[12];
    float* out = (float*)d_out;

    // workspace layout (floats): xa[3*M*R] | q[M*C] | k[M*C] | v[M*C] | o[M*C]
    float* ws = (float*)d_ws;
    float* xa = ws;
    float* q  = ws + (size_t)3 * MM * RR;
    float* k  = q + (size_t)MM * CC;
    float* v  = k + (size_t)MM * CC;
    float* ao = v + (size_t)MM * CC;

    lora_down<<<MM, 192, 0, stream>>>(x, la_q, la_k, la_v, bw, xa);
    qkv_gemm<<<dim3(CC / 128, MM / 128, 3), 256, 0, stream>>>(
        x, Wq, Wk, Wv, xa, lb_q, lb_k, lb_v, q, k, v);
    attn_kernel<<<dim3(NN / 64, BB * HH), 256, 0, stream>>>(q, k, v, ao);
    proj_gemm<<<dim3(CC / 128, MM / 128), 256, 0, stream>>>(ao, Wp, bp, out);
}

// Round 2
// 331.431 us; speedup vs baseline: 3.6116x; 3.6116x over previous
//
#include <hip/hip_runtime.h>

// Problem constants
#define BB 8
#define NN 1024
#define CC 768
#define HH 12
#define HD 64
#define RR 16
#define MM (BB * NN)   // 8192 tokens
#define WSZ (CC * CC)  // 589824 elements per weight matrix

// softmax scale folded with log2(e) for exp2f: HD^-0.5 * 1.4426950408889634
#define KSC 0.18033688011112042f

typedef short bf16x8 __attribute__((ext_vector_type(8)));
typedef short bf16x4 __attribute__((ext_vector_type(4)));
typedef float f32x4 __attribute__((ext_vector_type(4)));

__device__ __forceinline__ unsigned short f2bf(float f) {
    unsigned u = __builtin_bit_cast(unsigned, f);
    unsigned r = (u + 0x7FFFu + ((u >> 16) & 1u)) >> 16;
    return (unsigned short)r;
}
__device__ __forceinline__ float bf2f(unsigned short s) {
    return __builtin_bit_cast(float, ((unsigned)s) << 16);
}

// ---------------------------------------------------------------------------
// prep_w: We_z = W_z + bw[z] * la_z @ lb_z  (z<3), We_3 = Wp.
// Output TRANSPOSED bf16 hi/lo: Wt[z][n][k].  64x64 tiles, LDS transpose.
// ---------------------------------------------------------------------------
__global__ __launch_bounds__(256) void prep_w(
    const float* __restrict__ Wq, const float* __restrict__ Wk,
    const float* __restrict__ Wv, const float* __restrict__ Wp,
    const float* __restrict__ la_q, const float* __restrict__ lb_q,
    const float* __restrict__ la_k, const float* __restrict__ lb_k,
    const float* __restrict__ la_v, const float* __restrict__ lb_v,
    const float* __restrict__ bw, short* __restrict__ wt_hi,
    short* __restrict__ wt_lo) {
    __shared__ float laS[64][16];
    __shared__ float lbS[16][64];
    __shared__ float T[64][65];

    const int z = blockIdx.z;
    const int k0 = blockIdx.y * 64, n0 = blockIdx.x * 64;
    const int tid = threadIdx.x;

    const float* W = (z == 0) ? Wq : (z == 1) ? Wk : (z == 2) ? Wv : Wp;
    const float* la = (z == 0) ? la_q : (z == 1) ? la_k : la_v;
    const float* lb = (z == 0) ? lb_q : (z == 1) ? lb_k : lb_v;
    const float bwz = (z < 3) ? bw[z] : 0.f;

    if (z < 3) {
        #pragma unroll
        for (int e = 0; e < 4; ++e) {  // 1024 la elems
            int idx = tid + 256 * e;
            laS[idx >> 4][idx & 15] = la[(size_t)(k0 + (idx >> 4)) * RR + (idx & 15)];
            lbS[idx >> 6][idx & 63] = lb[(size_t)(idx >> 6) * CC + n0 + (idx & 63)];
        }
    }
    __syncthreads();

    #pragma unroll
    for (int e = 0; e < 16; ++e) {
        int idx = tid + 256 * e;
        int row = idx >> 6, col = idx & 63;
        float v = W[(size_t)(k0 + row) * CC + n0 + col];
        if (z < 3) {
            float s = 0.f;
            #pragma unroll
            for (int r = 0; r < 16; ++r) s += laS[row][r] * lbS[r][col];
            v += bwz * s;
        }
        T[row][col] = v;
    }
    __syncthreads();

    short* oh = wt_hi + (size_t)z * WSZ;
    short* ol = wt_lo + (size_t)z * WSZ;
    #pragma unroll
    for (int e = 0; e < 16; ++e) {
        int idx = tid + 256 * e;
        int nrow = idx >> 6, kcol = idx & 63;
        float v = T[kcol][nrow];
        unsigned short hi = f2bf(v);
        unsigned short lo = f2bf(v - bf2f(hi));
        size_t off = (size_t)(n0 + nrow) * CC + k0 + kcol;
        oh[off] = (short)hi;
        ol[off] = (short)lo;
    }
}

// ---------------------------------------------------------------------------
// prep_cvt: fp32 -> bf16 hi/lo, elementwise (float4 granularity).
// ---------------------------------------------------------------------------
__global__ __launch_bounds__(256) void prep_cvt(const float* __restrict__ src,
                                                short* __restrict__ hi,
                                                short* __restrict__ lo, int n4) {
    int i = blockIdx.x * 256 + threadIdx.x;
    const int stride = gridDim.x * 256;
    for (; i < n4; i += stride) {
        f32x4 v = ((const f32x4*)src)[i];
        bf16x4 h, l;
        #pragma unroll
        for (int c = 0; c < 4; ++c) {
            unsigned short hh = f2bf(v[c]);
            h[c] = (short)hh;
            l[c] = (short)f2bf(v[c] - bf2f(hh));
        }
        ((bf16x4*)hi)[i] = h;
        ((bf16x4*)lo)[i] = l;
    }
}

// ---------------------------------------------------------------------------
// Shared split-bf16 MFMA GEMM core. TN layout: both A and B tiles are
// [row][K] with K contiguous (B rows = output columns, i.e. B^T storage).
// Tile 128x128, BK=32, 4 waves (2x2), 16x16x32 MFMA, 3 mfma per frag pair
// (hh + hl + lh; lo*lo dropped).  LDS row stride 40 shorts (80B: 2-way max).
// ---------------------------------------------------------------------------
#define LW 40

__device__ __forceinline__ void gemm_core(
    const short* __restrict__ gAh, const short* __restrict__ gAl, int rowA0,
    const short* __restrict__ gBh, const short* __restrict__ gBl, int rowB0,
    short* AsH, short* AsL, short* BsH, short* BsL, f32x4 acc[4][4]) {
    const int tid = threadIdx.x;
    const int lane = tid & 63;
    const int w = tid >> 6;
    const int wm = w >> 1, wn = w & 1;
    const int p = lane & 15, g = lane >> 4;

    const int srow = tid >> 2;         // staging row (0..63, +64)
    const int scc = (tid & 3) * 8;     // staging col (shorts)

    for (int kt = 0; kt < CC; kt += 32) {
        #pragma unroll
        for (int q = 0; q < 2; ++q) {
            int row = srow + 64 * q;
            size_t ga = (size_t)(rowA0 + row) * CC + kt + scc;
            size_t gb = (size_t)(rowB0 + row) * CC + kt + scc;
            bf16x8 ah = *(const bf16x8*)(gAh + ga);
            bf16x8 al = *(const bf16x8*)(gAl + ga);
            bf16x8 bh = *(const bf16x8*)(gBh + gb);
            bf16x8 bl = *(const bf16x8*)(gBl + gb);
            *(bf16x8*)(AsH + row * LW + scc) = ah;
            *(bf16x8*)(AsL + row * LW + scc) = al;
            *(bf16x8*)(BsH + row * LW + scc) = bh;
            *(bf16x8*)(BsL + row * LW + scc) = bl;
        }
        __syncthreads();

        bf16x8 a_h[4], a_l[4], b_h[4], b_l[4];
        #pragma unroll
        for (int i = 0; i < 4; ++i) {
            int arow = wm * 64 + i * 16 + p;
            int brow = wn * 64 + i * 16 + p;
            a_h[i] = *(const bf16x8*)(AsH + arow * LW + g * 8);
            a_l[i] = *(const bf16x8*)(AsL + arow * LW + g * 8);
            b_h[i] = *(const bf16x8*)(BsH + brow * LW + g * 8);
            b_l[i] = *(const bf16x8*)(BsL + brow * LW + g * 8);
        }
        #pragma unroll
        for (int i = 0; i < 4; ++i) {
            #pragma unroll
            for (int j = 0; j < 4; ++j) {
                acc[i][j] = __builtin_amdgcn_mfma_f32_16x16x32_bf16(
                    a_h[i], b_h[j], acc[i][j], 0, 0, 0);
                acc[i][j] = __builtin_amdgcn_mfma_f32_16x16x32_bf16(
                    a_h[i], b_l[j], acc[i][j], 0, 0, 0);
                acc[i][j] = __builtin_amdgcn_mfma_f32_16x16x32_bf16(
                    a_l[i], b_h[j], acc[i][j], 0, 0, 0);
            }
        }
        __syncthreads();
    }
}

// ---------------------------------------------------------------------------
// gemm_qkv: z=0/1 -> q/k stored bf16 [B,H,N,HD]; z=2 -> V^T via swapped
// operands (out^T = We_v^T * x^T), stored bf16 [B,H,HD,N].
// ---------------------------------------------------------------------------
__global__ __launch_bounds__(256, 2) void gemm_qkv(
    const short* __restrict__ xh, const short* __restrict__ xl,
    const short* __restrict__ wth, const short* __restrict__ wtl,
    short* __restrict__ qb, short* __restrict__ kb, short* __restrict__ vtb) {
    __shared__ __align__(16) short AsH[128 * LW], AsL[128 * LW];
    __shared__ __align__(16) short BsH[128 * LW], BsL[128 * LW];

    const int z = blockIdx.z;
    const int m0 = blockIdx.y * 128, c0 = blockIdx.x * 128;
    const short* wzh = wth + (size_t)z * WSZ;
    const short* wzl = wtl + (size_t)z * WSZ;

    f32x4 acc[4][4];
    const f32x4 z4 = {0.f, 0.f, 0.f, 0.f};
    #pragma unroll
    for (int i = 0; i < 4; ++i)
        #pragma unroll
        for (int j = 0; j < 4; ++j) acc[i][j] = z4;

    const int lane = threadIdx.x & 63, w = threadIdx.x >> 6;
    const int wm = w >> 1, wn = w & 1, p = lane & 15, g = lane >> 4;

    if (z < 2) {
        gemm_core(xh, xl, m0, wzh, wzl, c0, AsH, AsL, BsH, BsL, acc);
        short* dst = (z == 0) ? qb : kb;
        #pragma unroll
        for (int i = 0; i < 4; ++i) {
            #pragma unroll
            for (int r = 0; r < 4; ++r) {
                int m = m0 + wm * 64 + i * 16 + 4 * g + r;
                int b = m >> 10, n = m & 1023;
                #pragma unroll
                for (int j = 0; j < 4; ++j) {
                    int c = c0 + wn * 64 + j * 16 + p;
                    int h = c >> 6, d = c & 63;
                    dst[(((size_t)(b * HH + h)) * NN + n) * HD + d] =
                        (short)f2bf(acc[i][j][r]);
                }
            }
        }
    } else {
        gemm_core(wzh, wzl, c0, xh, xl, m0, AsH, AsL, BsH, BsL, acc);
        #pragma unroll
        for (int i = 0; i < 4; ++i) {
            #pragma unroll
            for (int r = 0; r < 4; ++r) {
                int c = c0 + wm * 64 + i * 16 + 4 * g + r;
                int h = c >> 6, d = c & 63;
                #pragma unroll
                for (int j = 0; j < 4; ++j) {
                    int m = m0 + wn * 64 + j * 16 + p;
                    int b = m >> 10, n = m & 1023;
                    vtb[(((size_t)(b * HH + h)) * HD + d) * NN + n] =
                        (short)f2bf(acc[i][j][r]);
                }
            }
        }
    }
}

// ---------------------------------------------------------------------------
// attn: bf16 MFMA flash attention. Block = (b,h) x 64 q-rows, 4 waves x 16 q.
// S^T = K*Q^T (lane's softmax row = lane&15), P via per-wave LDS tile,
// PV reads V^T tile (staged from vtb). Output stored as bf16 hi/lo [B,N,C].
// ---------------------------------------------------------------------------
#define AW 72

__global__ __launch_bounds__(256) void attn(const short* __restrict__ qb,
                                            const short* __restrict__ kb,
                                            const short* __restrict__ vtb,
                                            short* __restrict__ aoh,
                                            short* __restrict__ aol) {
    __shared__ __align__(16) short Qs[64 * AW], Ks[64 * AW], Vts[64 * AW];
    __shared__ __align__(16) short Ps[4][16 * AW];

    const int bh = blockIdx.y, q0 = blockIdx.x * 64;
    const int tid = threadIdx.x, lane = tid & 63, w = tid >> 6;
    const int p = lane & 15, g = lane >> 4;
    const short* qp = qb + (size_t)bh * NN * HD;
    const short* kp = kb + (size_t)bh * NN * HD;
    const short* vp = vtb + (size_t)bh * NN * HD;

    #pragma unroll
    for (int e = 0; e < 2; ++e) {
        int idx = tid + 256 * e;
        int row = idx >> 3, c8 = (idx & 7) * 8;
        *(bf16x8*)(Qs + row * AW + c8) =
            *(const bf16x8*)(qp + (size_t)(q0 + row) * HD + c8);
    }
    __syncthreads();
    bf16x8 bQ[2];
    #pragma unroll
    for (int ks = 0; ks < 2; ++ks)
        bQ[ks] = *(const bf16x8*)(Qs + (w * 16 + p) * AW + g * 8 + 32 * ks);

    float m_run = -1e30f, l_run = 0.f;
    f32x4 oacc[4];
    const f32x4 z4 = {0.f, 0.f, 0.f, 0.f};
    #pragma unroll
    for (int df = 0; df < 4; ++df) oacc[df] = z4;
    short* Pw = &Ps[w][0];

    for (int t = 0; t < NN / 64; ++t) {
        if (t) __syncthreads();
        const int j0 = t * 64;
        #pragma unroll
        for (int e = 0; e < 2; ++e) {
            int idx = tid + 256 * e;
            int row = idx >> 3, c8 = (idx & 7) * 8;
            *(bf16x8*)(Ks + row * AW + c8) =
                *(const bf16x8*)(kp + (size_t)(j0 + row) * HD + c8);
            *(bf16x8*)(Vts + row * AW + c8) =
                *(const bf16x8*)(vp + (size_t)row * NN + j0 + c8);
        }
        __syncthreads();

        // S^T = K * Q^T : lane holds S[q=p][j = 4g+r+16jf]
        f32x4 sacc[4];
        #pragma unroll
        for (int jf = 0; jf < 4; ++jf) sacc[jf] = z4;
        #pragma unroll
        for (int ks = 0; ks < 2; ++ks) {
            #pragma unroll
            for (int jf = 0; jf < 4; ++jf) {
                bf16x8 aK =
                    *(const bf16x8*)(Ks + (jf * 16 + p) * AW + g * 8 + 32 * ks);
                sacc[jf] = __builtin_amdgcn_mfma_f32_16x16x32_bf16(
                    aK, bQ[ks], sacc[jf], 0, 0, 0);
            }
        }

        // online softmax over j (raw scores; scale folded into exp2)
        float tmax = -1e30f;
        #pragma unroll
        for (int jf = 0; jf < 4; ++jf)
            #pragma unroll
            for (int r = 0; r < 4; ++r) tmax = fmaxf(tmax, sacc[jf][r]);
        tmax = fmaxf(tmax, __shfl_xor(tmax, 16));
        tmax = fmaxf(tmax, __shfl_xor(tmax, 32));
        const float mnew = fmaxf(m_run, tmax);
        const float fac = exp2f((m_run - mnew) * KSC);
        m_run = mnew;
        float lsum = 0.f;
        bf16x4 pk[4];
        #pragma unroll
        for (int jf = 0; jf < 4; ++jf) {
            #pragma unroll
            for (int r = 0; r < 4; ++r) {
                float e = exp2f((sacc[jf][r] - mnew) * KSC);
                lsum += e;
                pk[jf][r] = (short)f2bf(e);
            }
        }
        lsum += __shfl_xor(lsum, 16);
        lsum += __shfl_xor(lsum, 32);
        l_run = l_run * fac + lsum;

        #pragma unroll
        for (int jf = 0; jf < 4; ++jf)
            *(bf16x4*)(Pw + p * AW + jf * 16 + 4 * g) = pk[jf];
        asm volatile("s_waitcnt lgkmcnt(0)" ::: "memory");
        __builtin_amdgcn_sched_barrier(0);

        // rescale O by fac (per output row q = 4g+r)
        #pragma unroll
        for (int r = 0; r < 4; ++r) {
            float fr = __shfl(fac, 4 * g + r, 16);
            #pragma unroll
            for (int df = 0; df < 4; ++df) oacc[df][r] *= fr;
        }

        // PV: OUT = P*V, B-frags from V^T tile
        #pragma unroll
        for (int ks = 0; ks < 2; ++ks) {
            bf16x8 aP = *(const bf16x8*)(Pw + p * AW + g * 8 + 32 * ks);
            #pragma unroll
            for (int df = 0; df < 4; ++df) {
                bf16x8 bV =
                    *(const bf16x8*)(Vts + (df * 16 + p) * AW + g * 8 + 32 * ks);
                oacc[df] = __builtin_amdgcn_mfma_f32_16x16x32_bf16(
                    aP, bV, oacc[df], 0, 0, 0);
            }
        }
    }

    const float inv = 1.f / l_run;  // lane's q = p
    const int b = bh / HH, h = bh % HH;
    #pragma unroll
    for (int r = 0; r < 4; ++r) {
        float ir = __shfl(inv, 4 * g + r, 16);
        int n = q0 + w * 16 + 4 * g + r;
        #pragma unroll
        for (int df = 0; df < 4; ++df) {
            float v = oacc[df][r] * ir;
            unsigned short hi = f2bf(v);
            unsigned short lo = f2bf(v - bf2f(hi));
            size_t off = ((size_t)(b * NN + n)) * CC + h * HD + df * 16 + p;
            aoh[off] = (short)hi;
            aol[off] = (short)lo;
        }
    }
}

// ---------------------------------------------------------------------------
// gemm_proj: out = ao @ We_p + bp  (fp32 out)
// ---------------------------------------------------------------------------
__global__ __launch_bounds__(256, 2) void gemm_proj(
    const short* __restrict__ aoh, const short* __restrict__ aol,
    const short* __restrict__ wth, const short* __restrict__ wtl,
    const float* __restrict__ bp, float* __restrict__ out) {
    __shared__ __align__(16) short AsH[128 * LW], AsL[128 * LW];
    __shared__ __align__(16) short BsH[128 * LW], BsL[128 * LW];

    const int m0 = blockIdx.y * 128, c0 = blockIdx.x * 128;
    const short* wph = wth + (size_t)3 * WSZ;
    const short* wpl = wtl + (size_t)3 * WSZ;

    f32x4 acc[4][4];
    const f32x4 z4 = {0.f, 0.f, 0.f, 0.f};
    #pragma unroll
    for (int i = 0; i < 4; ++i)
        #pragma unroll
        for (int j = 0; j < 4; ++j) acc[i][j] = z4;

    gemm_core(aoh, aol, m0, wph, wpl, c0, AsH, AsL, BsH, BsL, acc);

    const int lane = threadIdx.x & 63, w = threadIdx.x >> 6;
    const int wm = w >> 1, wn = w & 1, p = lane & 15, g = lane >> 4;

    float bpv[4];
    #pragma unroll
    for (int j = 0; j < 4; ++j) bpv[j] = bp[c0 + wn * 64 + j * 16 + p];

    #pragma unroll
    for (int i = 0; i < 4; ++i) {
        #pragma unroll
        for (int r = 0; r < 4; ++r) {
            int m = m0 + wm * 64 + i * 16 + 4 * g + r;
            #pragma unroll
            for (int j = 0; j < 4; ++j) {
                int c = c0 + wn * 64 + j * 16 + p;
                out[(size_t)m * CC + c] = acc[i][j][r] + bpv[j];
            }
        }
    }
}

// ---------------------------------------------------------------------------
extern "C" void kernel_launch(void* const* d_in, const int* in_sizes, int n_in,
                              void* d_out, int out_size, void* d_ws,
                              size_t ws_size, hipStream_t stream) {
    const float* x = (const float*)d_in[0];
    const float* Wq = (const float*)d_in[1];
    const float* Wk = (const float*)d_in[2];
    const float* Wv = (const float*)d_in[3];
    const float* Wp = (const float*)d_in[4];
    const float* bp = (const float*)d_in[5];
    const float* la_q = (const float*)d_in[6];
    const float* lb_q = (const float*)d_in[7];
    const float* la_k = (const float*)d_in[8];
    const float* lb_k = (const float*)d_in[9];
    const float* la_v = (const float*)d_in[10];
    const float* lb_v = (const float*)d_in[11];
    const float* bw = (const float*)d_in[12];
    float* out = (float*)d_out;

    // workspace layout (shorts):
    short* ws = (short*)d_ws;
    short* wt_hi = ws;                        // 4*WSZ
    short* wt_lo = wt_hi + (size_t)4 * WSZ;   // 4*WSZ
    short* x_hi = wt_lo + (size_t)4 * WSZ;    // MM*CC
    short* x_lo = x_hi + (size_t)MM * CC;
    short* qbuf = x_lo + (size_t)MM * CC;     // [B,H,N,HD]
    short* kbuf = qbuf + (size_t)MM * CC;
    short* vtbuf = kbuf + (size_t)MM * CC;    // [B,H,HD,N]
    short* aoh = vtbuf + (size_t)MM * CC;     // [B,N,C] hi
    short* aol = aoh + (size_t)MM * CC;       // [B,N,C] lo

    prep_w<<<dim3(CC / 64, CC / 64, 4), 256, 0, stream>>>(
        Wq, Wk, Wv, Wp, la_q, lb_q, la_k, lb_k, la_v, lb_v, bw, wt_hi, wt_lo);
    prep_cvt<<<2048, 256, 0, stream>>>(x, x_hi, x_lo, MM * CC / 4);
    gemm_qkv<<<dim3(CC / 128, MM / 128, 3), 256, 0, stream>>>(
        x_hi, x_lo, wt_hi, wt_lo, qbuf, kbuf, vtbuf);
    attn<<<dim3(NN / 64, BB * HH), 256, 0, stream>>>(qbuf, kbuf, vtbuf, aoh, aol);
    gemm_proj<<<dim3(CC / 128, MM / 128), 256, 0, stream>>>(aoh, aol, wt_hi,
                                                            wt_lo, bp, out);
}